// Round 1
// 161.920 us; speedup vs baseline: 1.1837x; 1.1837x over previous
//
#include <hip/hip_runtime.h>

#define MUL 16
#define NPAIR 136
#define NTILE 25          // 10 s-tiles + 10 pq-tiles + 5 t-tiles

typedef __bf16 bf16x8 __attribute__((ext_vector_type(8)));
typedef float  f32x4  __attribute__((ext_vector_type(4)));

// pair p (0..135) -> (u<=v). p>=NPAIR maps to (0,0): its B slots are zero, so
// the A-side garbage contributes nothing (finite*0 == 0).
__device__ __forceinline__ void uv_of(int p, int& u, int& v) {
    if (p >= NPAIR) { u = 0; v = 0; return; }
    int uu = 0, rem = p;
    while (rem >= MUL - uu) { rem -= MUL - uu; ++uu; }
    u = uu; v = uu + rem;
}

// ---------------------------------------------------------------------------
// prep: gather-style, one thread per B-fragment (tile,lane) = 16 bytes.
// Superchunk c covers pairs 32c+j, j=0..31.  Lane (q,w) of a tile holds
// k in [8q,8q+8).  Mapping:
//   s  tiles 2c+b   (b=(j>>2)&1): pair j=8q+4b+i -> k=8q+2i (f000), +1 (f110)
//   pq tiles 10+2c+b: same pairs  -> k=8q+2i (fuv), +1 (fvu)
//   t  tiles 20+c:    pair j=8q+e -> k=8q+e (f112)
// ---------------------------------------------------------------------------
__global__ void prep_weights(const float* __restrict__ w000,
                             const float* __restrict__ w101,
                             const float* __restrict__ w110,
                             const float* __restrict__ w112,
                             __bf16* __restrict__ wt) {
    const int gid = blockIdx.x * 256 + threadIdx.x;
    if (gid >= NTILE * 64) return;
    const int T = gid >> 6, lane = gid & 63;
    const int q = lane >> 4, w = lane & 15;

    const float A000   = 0.044194173824159216f;   // sqrt(1/(2*16*16))
    const float A110   = 0.025515518153991442f;   // A000/sqrt(3)
    const float A101   = 0.0625f;
    const float A112C1 = 0.044194173824159216f;   // A112/sqrt(10)

    bf16x8 frag = {};
    if (T < 10) {
        const int c = T >> 1, b = T & 1;
#pragma unroll
        for (int i = 0; i < 4; ++i) {
            const int p = 32 * c + 8 * q + 4 * b + i;
            if (p < NPAIR) {
                int u, v; uv_of(p, u, v);
                const int uvw = (u * MUL + v) * MUL + w;
                const int vuw = (v * MUL + u) * MUL + w;
                float f000, f110;
                if (u == v) { f000 = A000 * w000[uvw]; f110 = A110 * w110[uvw]; }
                else        { f000 = A000 * (w000[uvw] + w000[vuw]);
                              f110 = A110 * (w110[uvw] + w110[vuw]); }
                frag[2 * i]     = (__bf16)f000;
                frag[2 * i + 1] = (__bf16)f110;
            }
        }
    } else if (T < 20) {
        const int c = (T - 10) >> 1, b = (T - 10) & 1;
#pragma unroll
        for (int i = 0; i < 4; ++i) {
            const int p = 32 * c + 8 * q + 4 * b + i;
            if (p < NPAIR) {
                int u, v; uv_of(p, u, v);
                const int uvw = (u * MUL + v) * MUL + w;
                const int vuw = (v * MUL + u) * MUL + w;
                frag[2 * i]     = (__bf16)(A101 * w101[uvw]);
                frag[2 * i + 1] = (__bf16)((u == v) ? 0.f : A101 * w101[vuw]);
            }
        }
    } else {
        const int c = T - 20;
#pragma unroll
        for (int e = 0; e < 8; ++e) {
            const int p = 32 * c + 8 * q + e;
            if (p < NPAIR) {
                int u, v; uv_of(p, u, v);
                const int uvw = (u * MUL + v) * MUL + w;
                const int vuw = (v * MUL + u) * MUL + w;
                const float f112 = (u == v) ? A112C1 * w112[uvw]
                                            : A112C1 * (w112[uvw] + w112[vuw]);
                frag[e] = (__bf16)f112;
            }
        }
    }
    ((bf16x8*)wt)[T * 64 + lane] = frag;
}

// ---------------------------------------------------------------------------
// Main kernel: one WAVE owns 16 nodes end-to-end (block = 4 waves = 64 nodes).
// No __syncthreads after the x-staging barrier: each lane (m=lane&15, q=lane>>4)
// computes its own A-fragment slots k in [8q,8q+8) in registers and the wave
// issues its own MFMAs.  Per superchunk (32 pairs, 8 per lane): each pair's
// xu/xv is read from LDS ONCE and feeds s, pq(x3) and t(x5) families.
// ---------------------------------------------------------------------------
#define SQ3f  1.7320508075688772f
#define ISQ3f 0.5773502691896258f

template<int E>
__device__ __forceinline__ void pair_feats(int d, const float* __restrict__ xrow,
        bf16x8& fS, bf16x8& f0, bf16x8& f1, bf16x8& f2,
        bf16x8& t0, bf16x8& t1, bf16x8& t2, bf16x8& t3, bf16x8& t4) {
    constexpr int sh = (E & 1) * 16;
    const int u = (d >> sh) & 0xff;
    const int v = (d >> (sh + 8)) & 0xff;
    const float4 xu = *(const float4*)(xrow + 4 * u);   // quad: x0[u], x1[u][0..2]
    const float4 xv = *(const float4*)(xrow + 4 * v);
    const float o00 = xu.y * xv.y, o01 = xu.y * xv.z, o02 = xu.y * xv.w;
    const float o10 = xu.z * xv.y, o11 = xu.z * xv.z, o12 = xu.z * xv.w;
    const float o20 = xu.w * xv.y, o21 = xu.w * xv.z, o22 = xu.w * xv.w;
    const float s1 = (o00 + o11) + o22;
    constexpr int s2 = (E & 3) * 2;
    fS[s2]     = (__bf16)(xu.x * xv.x);
    fS[s2 + 1] = (__bf16)s1;
    f0[s2]     = (__bf16)(xu.y * xv.x);  f0[s2 + 1] = (__bf16)(xv.y * xu.x);
    f1[s2]     = (__bf16)(xu.z * xv.x);  f1[s2 + 1] = (__bf16)(xv.z * xu.x);
    f2[s2]     = (__bf16)(xu.w * xv.x);  f2[s2 + 1] = (__bf16)(xv.w * xu.x);
    t0[E] = (__bf16)(o01 + o10);
    t1[E] = (__bf16)(o02 + o20);
    t2[E] = (__bf16)(o12 + o21);
    t3[E] = (__bf16)(o00 - o11);
    t4[E] = (__bf16)(SQ3f * o22 - ISQ3f * s1);
}

__launch_bounds__(256, 3)
__global__ void tsq_kernel(const float* __restrict__ feats,
                           const float* __restrict__ msgs,
                           const __bf16* __restrict__ wtiles,
                           float* __restrict__ out) {
    // x quads: node-stride 68 dwords (68 % 32 == 4 spreads nodes over banks ->
    // the main-loop b128 reads are conflict-free; 4 q-lanes broadcast).
    __shared__ __align__(16) float xq[64 * 68];        // 17408 B
    __shared__ __align__(16) int   uvt[80];            // 160 pairs, packed u|v bytes

    const int tid = threadIdx.x;
    const long long blockNode = (long long)blockIdx.x * 64;

    if (tid < 80) {
        int u0, v0, u1, v1;
        uv_of(2 * tid,     u0, v0);
        uv_of(2 * tid + 1, u1, v1);
        uvt[tid] = u0 | (v0 << 8) | (u1 << 16) | (v1 << 24);
    }

    // coalesced load of feats+msgs (64 nodes x 64 f32), scatter to quad layout:
    // f<16 -> (v=f, slot 0);  f>=16 -> g=f-16, v=g/3, slot 1+g%3
    {
        const float4* f4p = (const float4*)(feats + blockNode * 64);
        const float4* m4p = (const float4*)(msgs  + blockNode * 64);
#pragma unroll
        for (int r = 0; r < 4; ++r) {
            const int li = r * 256 + tid;              // 0..1023
            const int nd = li >> 4, f4 = li & 15;
            const float4 a = f4p[li];
            const float4 b = m4p[li];
            const float vals[4] = {a.x + b.x, a.y + b.y, a.z + b.z, a.w + b.w};
#pragma unroll
            for (int jj = 0; jj < 4; ++jj) {
                const int f = 4 * f4 + jj;
                int dst;
                if (f < 16) dst = nd * 68 + 4 * f;
                else {
                    const int g = f - 16;
                    const int v3 = (g * 171) >> 9;     // g/3 for g<48
                    dst = nd * 68 + 4 * v3 + 1 + (g - 3 * v3);
                }
                xq[dst] = vals[jj];
            }
        }
    }
    __syncthreads();   // the ONLY barrier

    const int lane = tid & 63;
    const int wid  = tid >> 6;
    const int m = lane & 15, q = lane >> 4;
    const float* xrow = xq + (wid * 16 + m) * 68;
    const bf16x8* wb = (const bf16x8*)wtiles;

    f32x4 accS  = {0.f, 0.f, 0.f, 0.f};
    f32x4 accP0 = {0.f, 0.f, 0.f, 0.f};
    f32x4 accP1 = {0.f, 0.f, 0.f, 0.f};
    f32x4 accP2 = {0.f, 0.f, 0.f, 0.f};
    f32x4 accT0 = {0.f, 0.f, 0.f, 0.f};
    f32x4 accT1 = {0.f, 0.f, 0.f, 0.f};
    f32x4 accT2 = {0.f, 0.f, 0.f, 0.f};
    f32x4 accT3 = {0.f, 0.f, 0.f, 0.f};
    f32x4 accT4 = {0.f, 0.f, 0.f, 0.f};

#pragma unroll
    for (int c = 0; c < 5; ++c) {
        // this lane's 8 pairs (32c+8q .. +7), 2 bytes each = one b128 read
        const int4 uvd = *(const int4*)((const char*)uvt + 64 * c + 16 * q);
        bf16x8 t0 = {}, t1 = {}, t2 = {}, t3 = {}, t4 = {};
        {
            const bf16x8 bS = wb[(2 * c) * 64 + lane];
            const bf16x8 bP = wb[(10 + 2 * c) * 64 + lane];
            bf16x8 fS, f0, f1, f2;
            pair_feats<0>(uvd.x, xrow, fS, f0, f1, f2, t0, t1, t2, t3, t4);
            pair_feats<1>(uvd.x, xrow, fS, f0, f1, f2, t0, t1, t2, t3, t4);
            pair_feats<2>(uvd.y, xrow, fS, f0, f1, f2, t0, t1, t2, t3, t4);
            pair_feats<3>(uvd.y, xrow, fS, f0, f1, f2, t0, t1, t2, t3, t4);
            accS  = __builtin_amdgcn_mfma_f32_16x16x32_bf16(fS, bS, accS,  0, 0, 0);
            accP0 = __builtin_amdgcn_mfma_f32_16x16x32_bf16(f0, bP, accP0, 0, 0, 0);
            accP1 = __builtin_amdgcn_mfma_f32_16x16x32_bf16(f1, bP, accP1, 0, 0, 0);
            accP2 = __builtin_amdgcn_mfma_f32_16x16x32_bf16(f2, bP, accP2, 0, 0, 0);
        }
        {
            const bf16x8 bS = wb[(2 * c + 1) * 64 + lane];
            const bf16x8 bP = wb[(11 + 2 * c) * 64 + lane];
            bf16x8 fS, f0, f1, f2;
            pair_feats<4>(uvd.z, xrow, fS, f0, f1, f2, t0, t1, t2, t3, t4);
            pair_feats<5>(uvd.z, xrow, fS, f0, f1, f2, t0, t1, t2, t3, t4);
            pair_feats<6>(uvd.w, xrow, fS, f0, f1, f2, t0, t1, t2, t3, t4);
            pair_feats<7>(uvd.w, xrow, fS, f0, f1, f2, t0, t1, t2, t3, t4);
            accS  = __builtin_amdgcn_mfma_f32_16x16x32_bf16(fS, bS, accS,  0, 0, 0);
            accP0 = __builtin_amdgcn_mfma_f32_16x16x32_bf16(f0, bP, accP0, 0, 0, 0);
            accP1 = __builtin_amdgcn_mfma_f32_16x16x32_bf16(f1, bP, accP1, 0, 0, 0);
            accP2 = __builtin_amdgcn_mfma_f32_16x16x32_bf16(f2, bP, accP2, 0, 0, 0);
        }
        const bf16x8 bT = wb[(20 + c) * 64 + lane];
        accT0 = __builtin_amdgcn_mfma_f32_16x16x32_bf16(t0, bT, accT0, 0, 0, 0);
        accT1 = __builtin_amdgcn_mfma_f32_16x16x32_bf16(t1, bT, accT1, 0, 0, 0);
        accT2 = __builtin_amdgcn_mfma_f32_16x16x32_bf16(t2, bT, accT2, 0, 0, 0);
        accT3 = __builtin_amdgcn_mfma_f32_16x16x32_bf16(t3, bT, accT3, 0, 0, 0);
        accT4 = __builtin_amdgcn_mfma_f32_16x16x32_bf16(t4, bT, accT4, 0, 0, 0);
    }

    // epilogue: C/D col = lane&15 = output idx w, row = q*4+r = node-in-wave
#pragma unroll
    for (int r = 0; r < 4; ++r) {
        float* ob = out + (blockNode + wid * 16 + q * 4 + r) * 144;
        ob[m]              = accS[r];
        ob[16 + 3 * m + 0] = accP0[r];
        ob[16 + 3 * m + 1] = accP1[r];
        ob[16 + 3 * m + 2] = accP2[r];
        ob[64 + 5 * m + 0] = accT0[r];
        ob[64 + 5 * m + 1] = accT1[r];
        ob[64 + 5 * m + 2] = accT2[r];
        ob[64 + 5 * m + 3] = accT3[r];
        ob[64 + 5 * m + 4] = accT4[r];
    }
}

extern "C" void kernel_launch(void* const* d_in, const int* in_sizes, int n_in,
                              void* d_out, int out_size, void* d_ws, size_t ws_size,
                              hipStream_t stream) {
    const float* feats = (const float*)d_in[0];
    const float* msgs  = (const float*)d_in[1];
    const float* w000  = (const float*)d_in[2];
    const float* w101  = (const float*)d_in[3];
    const float* w110  = (const float*)d_in[4];
    const float* w112  = (const float*)d_in[5];
    __bf16* wt = (__bf16*)d_ws;                 // 25*64*8 bf16 = 25600 B
    float* out = (float*)d_out;

    const int n = in_sizes[0] / (4 * MUL);      // 131072 nodes

    prep_weights<<<(NTILE * 64 + 255) / 256, 256, 0, stream>>>(w000, w101, w110, w112, wt);
    tsq_kernel<<<n / 64, 256, 0, stream>>>(feats, msgs, wt, out);
}